// Round 18
// baseline (5860.880 us; speedup 1.0000x reference)
//
#include <hip/hip_runtime.h>

typedef __attribute__((ext_vector_type(8))) short short8;
typedef __attribute__((ext_vector_type(4))) float f32x4;
typedef unsigned short u16;
typedef unsigned int u32;
typedef unsigned long long u64;

#define T_LEN 256
#define XSTEP_U16 32768      // x/y per-t: [kt:16][nt:4][512] u16 = 64KB
#define CHUNK_U16 512
#define HSLOT_U64 4096       // per (layer,sq) slot: 256 Qp x 16 n u64 = 32KB

// workspace layout (bytes)
#define OFF_X0 0u
#define SZ_X0 (256u * 65536u)   // 16MB
#define OFF_Y0 (OFF_X0 + SZ_X0)
#define SZ_Y0 SZ_X0             // 16MB
#define OFF_HD (OFF_Y0 + SZ_Y0)
#define SZ_HD (8u * 2u * 32768u)  // 8 (layer,sq) domains x 2 slots x 32KB
#define OFF_POOL (OFF_HD + SZ_HD)
#define SZ_POOL (512u * 64u * 4u)
#define OFF_YFLG (OFF_POOL + SZ_POOL)
#define SZ_YFLG (4u * 16u * 4u)   // [sq][16 units] packed u32

__device__ __forceinline__ u16 f2bf(float x) {
  unsigned u = __builtin_bit_cast(unsigned, x);
  return (u16)((u + 0x7fffu + ((u >> 16) & 1u)) >> 16);
}
__device__ __forceinline__ float sigf(float x) { return 1.f / (1.f + __expf(-x)); }
__device__ __forceinline__ float tanhfast(float x) {
  float e = __expf(2.f * x);
  return 1.f - 2.f / (e + 1.f);
}

// relaxed agent-scope (sc1, LLC-coherent) primitives
__device__ __forceinline__ u64 ld8_llc(const u64* p) {
  return __hip_atomic_load(p, __ATOMIC_RELAXED, __HIP_MEMORY_SCOPE_AGENT);
}
__device__ __forceinline__ void st8_llc(u64* p, u64 v) {
  __hip_atomic_store(p, v, __ATOMIC_RELAXED, __HIP_MEMORY_SCOPE_AGENT);
}
__device__ __forceinline__ short8 ld16_llc(const u16* p) {
  const u64* q = (const u64*)p;
  u64 lo = ld8_llc(q), hi = ld8_llc(q + 1);
  union { u64 v[2]; short8 s; } u;
  u.v[0] = lo; u.v[1] = hi;
  return u.s;
}
__device__ __forceinline__ void st2_llc(u16* p, u16 v) {
  __hip_atomic_store(p, v, __ATOMIC_RELAXED, __HIP_MEMORY_SCOPE_AGENT);
}
__device__ __forceinline__ void st4_llc(u32* p, u32 v) {
  __hip_atomic_store(p, v, __ATOMIC_RELAXED, __HIP_MEMORY_SCOPE_AGENT);
}
__device__ __forceinline__ u32 ld4_llc(const u32* p) {
  return __hip_atomic_load(p, __ATOMIC_RELAXED, __HIP_MEMORY_SCOPE_AGENT);
}
// poll 16 packed u32 flags (one line); lane i checks dword i&15
__device__ __forceinline__ void poll_sc1(const u32* base, int lane, u32 tgt) {
  const u32* pf = base + (lane & 15);
  for (;;) {
    u32 v = ld4_llc(pf);
    if (__all((int)(v >= tgt))) break;
    __builtin_amdgcn_s_sleep(1);
  }
  asm volatile("" ::: "memory");
}

__device__ __forceinline__ short8 cvt8(const float* src) {
  float4 lo = *(const float4*)src;
  float4 hi = *(const float4*)(src + 4);
  short8 fr;
  fr[0] = (short)f2bf(lo.x); fr[1] = (short)f2bf(lo.y);
  fr[2] = (short)f2bf(lo.z); fr[3] = (short)f2bf(lo.w);
  fr[4] = (short)f2bf(hi.x); fr[5] = (short)f2bf(hi.y);
  fr[6] = (short)f2bf(hi.z); fr[7] = (short)f2bf(hi.w);
  return fr;
}

// ---- embedding gather into MFMA-B fragment layout (bf16) ----
__global__ void gather_x0(const int* __restrict__ in_t, const float* __restrict__ emb,
                          u16* __restrict__ x0) {
  int gid = blockIdx.x * 256 + threadIdx.x;
  int c = gid >> 6, lane = gid & 63;
  int t = c >> 6, rem = c & 63;
  int kt = rem >> 2, nt = rem & 3;
  int b = nt * 16 + (lane & 15);
  int k0 = kt * 32 + ((lane >> 4) * 8);
  int row = in_t[b * T_LEN + t];
  *(short8*)(x0 + (size_t)c * CHUNK_U16 + lane * 8) =
      cvt8(emb + (size_t)row * 512 + k0);
}

// ---- persistent recurrent kernel: 32h x 16n units, single-barrier step ----
// 128 blocks x 512 threads. bid: g=bid&7 (layer=g>>2, sq=g&3), u=bid>>3 (0..15).
// Unit: h [32u,32u+32) (128 gate-rows, m=4*h_local+gate, 8 m-tiles) x samples
// [16sq,16sq+16), full K. Waves 0-3 x-side: kt [4w,4w+4), nt=sq. Waves 4-7
// h-side: e=w-4, real kt [4e,4e+4) via tagged u64s, tag-stripped in regs.
// Domain slot: [Qp:256][n:16] u64; Qp covers h pair (2Qp,2Qp+1); u64 =
// {c_even, c_odd, tag u32}; tag==t+1 published fire-and-forget at end of step t.
// Reduction: ds_add_f32 into double-buffered padded slab; ONE barrier/step.
// y certification amortized to every 4 steps (L1 trails <=4; pipeline ~260).
__global__ __launch_bounds__(512, 1) void lstm_persist(
    const float* __restrict__ wx, const float* __restrict__ bx,
    const float* __restrict__ wh, const float* __restrict__ bh,
    const u16* __restrict__ x0, u16* __restrict__ y0,
    u16* __restrict__ hd, float* __restrict__ pool, u32* __restrict__ yflg) {
  __shared__ float part[2][128][17];   // double-buffered padded slab = 17KB

  const int tid = threadIdx.x;
  const int w = tid >> 6, lane = tid & 63;
  const int q = lane >> 4, col = lane & 15;
  const int bid = blockIdx.x;
  const int g = bid & 7;
  const int layer = g >> 2, sq = g & 3;
  const int u = bid >> 3;          // 0..15
  const bool xside = (w < 4);
  const int e = w & 3;             // k-quarter for both sides

  // ---- weight fragments: 8 m-tiles x 4 real-kt = 128 regs (untagged) ----
  short8 af[8][4];
  {
    const int gt_a = col & 3, hsub = col >> 2;
    const float* wsel = xside ? wx : wh;
#pragma unroll
    for (int mt = 0; mt < 8; ++mt) {
      const int h_out = u * 32 + mt * 4 + hsub;
      const float* wrow = wsel + ((size_t)(layer * 4 + gt_a) * 512 + h_out) * 512;
#pragma unroll
      for (int ks = 0; ks < 4; ++ks)
        af[mt][ks] = cvt8(wrow + (e * 4 + ks) * 32 + q * 8);
    }
  }

  // zero both slab buffers
  for (int i = tid; i < 2 * 128 * 17; i += 512)
    ((float*)part)[i] = 0.f;

  // epilogue ownership: one (h_g = 32u + hl, sample n) per thread
  const int hl = tid >> 4, n = tid & 15;   // hl 0..31, n 0..15
  const int h_g = u * 32 + hl;
  float bias[4];
#pragma unroll
  for (int r = 0; r < 4; ++r)
    bias[r] = bx[(layer * 4 + r) * 512 + h_g] + bh[(layer * 4 + r) * 512 + h_g];
  // y fragment offset: b = 16*sq + n -> nt = sq, b&15 = n
  const size_t offY = ((size_t)((h_g >> 5) * 4 + sq) * 64 +
                       n + 16 * ((h_g >> 3) & 3)) * 8 + (h_g & 7);
  // tagged u64 index (even hl stores pair (h_g, h_g+1)): Qp = 16u + hl/2
  const size_t hoff = (size_t)(16 * u + (hl >> 1)) * 16 + n;

  const u16* xbase = layer ? y0 : x0;
  u64* hdl = (u64*)hd + (size_t)g * 2 * HSLOT_U64;
  u32* yf_own = yflg + sq * 16 + u;
  const u32* yf_grp = yflg + sq * 16;

  float cst = 0.f, opool = 0.f;
  __syncthreads();   // slabs zeroed

  for (int t = 0; t < T_LEN; ++t) {
    f32x4 acc[8] = {};
    if (xside) {
      if (layer == 1) poll_sc1(yf_grp, lane, (u32)(t + 1));
      const u16* xs = xbase + (size_t)t * XSTEP_U16;
#pragma unroll
      for (int ks = 0; ks < 4; ++ks) {
        const int ktl = e * 4 + ks;
        const u16* p = xs + ((size_t)(ktl * 4 + sq) * 64 + lane) * 8;
        short8 f = (layer == 0) ? *(const short8*)p : ld16_llc(p);
#pragma unroll
        for (int mt = 0; mt < 8; ++mt)
          acc[mt] = __builtin_amdgcn_mfma_f32_16x16x32_bf16(af[mt][ks], f,
                                                            acc[mt], 0, 0, 0);
      }
    } else {
      // ---- h-side: tagged retry read (16 u64/thread), then strip+repack ----
      const u64* hs = hdl + (size_t)(t & 1) * HSLOT_U64;
      const u32 tagv = (u32)t;
      u64 d0[4], d1[4], d2[4], d3[4];   // [kr]: Qp+0..3 (compile-time idx)
      for (;;) {
#pragma unroll
        for (int kr = 0; kr < 4; ++kr) {
          const int ktl = e * 4 + kr;
          const u64* b0 = hs + ((size_t)(ktl * 16 + 4 * q) * 16 + col);
          d0[kr] = ld8_llc(b0);
          d1[kr] = ld8_llc(b0 + 16);
          d2[kr] = ld8_llc(b0 + 32);
          d3[kr] = ld8_llc(b0 + 48);
        }
        int ok = 1;
#pragma unroll
        for (int kr = 0; kr < 4; ++kr)
          ok &= (int)(((u32)(d0[kr] >> 32) == tagv) &
                      ((u32)(d1[kr] >> 32) == tagv) &
                      ((u32)(d2[kr] >> 32) == tagv) &
                      ((u32)(d3[kr] >> 32) == tagv));
        if (__all(ok)) break;
        __builtin_amdgcn_s_sleep(1);
      }
#pragma unroll
      for (int kr = 0; kr < 4; ++kr) {
        union { u64 v[2]; short8 s; } uf;   // strip tags: keep low-32 halves
        uf.v[0] = (u64)(u32)d0[kr] | ((u64)(u32)d1[kr] << 32);
        uf.v[1] = (u64)(u32)d2[kr] | ((u64)(u32)d3[kr] << 32);
#pragma unroll
        for (int mt = 0; mt < 8; ++mt)
          acc[mt] = __builtin_amdgcn_mfma_f32_16x16x32_bf16(af[mt][kr], uf.s,
                                                            acc[mt], 0, 0, 0);
      }
    }
    // partials -> ds_add into slab[t&1] (C/D: col=sample, row = 4q + r)
    {
      float(*slab)[17] = part[t & 1];
#pragma unroll
      for (int mt = 0; mt < 8; ++mt)
#pragma unroll
        for (int r = 0; r < 4; ++r)
          atomicAdd(&slab[mt * 16 + q * 4 + r][col], acc[mt][r]);
    }
    const bool certstep = (layer == 0) && ((t & 3) == 0);
    if (certstep)
      asm volatile("s_waitcnt vmcnt(0)" ::: "memory");  // drain old y stores
    __syncthreads();   // THE barrier: adds complete (and cert drains done)
    if (certstep && tid == 1) st4_llc(yf_own, (u32)t);  // certifies y(0..t-1)

    // ---- epilogue: read own 4 gate values, re-zero, gates, stores ----
    float v[4];
    {
      float(*slab)[17] = part[t & 1];
#pragma unroll
      for (int gt = 0; gt < 4; ++gt) {
        v[gt] = slab[4 * hl + gt][n] + bias[gt];
        slab[4 * hl + gt][n] = 0.f;   // ready for step t+2
      }
    }
    const float ig = sigf(v[0]);
    const float fg = sigf(v[1]);
    const float gg = tanhfast(v[2]);
    const float og = sigf(v[3]);
    const float cn = fg * cst + ig * gg;   // c input = prev h_new (unpack bug)
    const float hn = og * tanhfast(cn);
    cst = hn;
    const float pcn = __shfl_xor(cn, 16, 64);  // partner (hl^1) c_new
    if ((hl & 1) == 0) {   // even-hl threads store the tagged pair u64
      u64* hdst = hdl + (size_t)((t + 1) & 1) * HSLOT_U64;
      u64 val = (u64)(u16)f2bf(cn) | ((u64)(u16)f2bf(pcn) << 16) |
                ((u64)(u32)(t + 1) << 32);
      st8_llc(hdst + hoff, val);         // fire-and-forget (bug: c_new is h-input)
    }
    if (layer == 0) {
      st2_llc(y0 + (size_t)t * XSTEP_U16 + offY, f2bf(og));  // o -> L1 input
    } else {
      opool += og;
    }
  }

  if (layer == 0) {
    // final y certification (certifies y(0..255)); without it L1 deadlocks
    asm volatile("s_waitcnt vmcnt(0)" ::: "memory");
    __syncthreads();
    if (tid == 1) st4_llc(yf_own, (u32)T_LEN);
  } else {
    pool[(size_t)h_g * 64 + sq * 16 + n] = opool;
  }
}

// ---- final pooled @ wo.T + bo -> sigmoid ----
__global__ void finalize_k(const float* __restrict__ pool, const float* __restrict__ wo,
                           const float* __restrict__ bo, float* __restrict__ out) {
  const int b = threadIdx.x;
  float s = 0.f;
  for (int h = 0; h < 512; ++h) s += pool[h * 64 + b] * wo[h];
  out[b] = sigf(s * (1.f / 256.f) + bo[0]);
}

extern "C" void kernel_launch(void* const* d_in, const int* in_sizes, int n_in,
                              void* d_out, int out_size, void* d_ws, size_t ws_size,
                              hipStream_t stream) {
  const int* in_t = (const int*)d_in[0];
  const float* emb = (const float*)d_in[1];
  const float* wx = (const float*)d_in[2];
  const float* bx = (const float*)d_in[3];
  const float* wh = (const float*)d_in[4];
  const float* bh = (const float*)d_in[5];
  const float* wo = (const float*)d_in[6];
  const float* bo = (const float*)d_in[7];
  float* out = (float*)d_out;
  char* ws = (char*)d_ws;
  u16* x0 = (u16*)(ws + OFF_X0);
  u16* y0 = (u16*)(ws + OFF_Y0);
  u16* hd = (u16*)(ws + OFF_HD);
  float* pool = (float*)(ws + OFF_POOL);
  u32* yflg = (u32*)(ws + OFF_YFLG);

  hipMemsetAsync(ws + OFF_HD, 0, SZ_HD, stream);     // h(0)=0, tags=0
  hipMemsetAsync(ws + OFF_YFLG, 0, SZ_YFLG, stream); // y flags
  gather_x0<<<4096, 256, 0, stream>>>(in_t, emb, x0);
  lstm_persist<<<128, 512, 0, stream>>>(wx, bx, wh, bh, x0, y0, hd, pool, yflg);
  finalize_k<<<1, 64, 0, stream>>>(pool, wo, bo, out);
}

// Round 19
// 708.229 us; speedup vs baseline: 8.2754x; 8.2754x over previous
//
#include <hip/hip_runtime.h>

typedef __attribute__((ext_vector_type(8))) short short8;
typedef __attribute__((ext_vector_type(4))) float f32x4;
typedef unsigned short u16;
typedef unsigned int u32;
typedef unsigned long long u64;

#define T_LEN 256
#define XSTEP_U16 32768      // x/y per-t: [kt:16][nt:4][512] u16 = 64KB
#define CHUNK_U16 512
#define HSLOT_U64 4096       // per (layer,sq) slot: 256 Qp x 16 n u64 = 32KB

// workspace layout (bytes)
#define OFF_X0 0u
#define SZ_X0 (256u * 65536u)   // 16MB
#define OFF_Y0 (OFF_X0 + SZ_X0)
#define SZ_Y0 SZ_X0             // 16MB
#define OFF_HD (OFF_Y0 + SZ_Y0)
#define SZ_HD (8u * 2u * 32768u)  // 8 (layer,sq) domains x 2 slots x 32KB
#define OFF_POOL (OFF_HD + SZ_HD)
#define SZ_POOL (512u * 64u * 4u)
#define OFF_YFLG (OFF_POOL + SZ_POOL)
#define SZ_YFLG (4u * 16u * 4u)   // [sq][16 units] packed u32

__device__ __forceinline__ u16 f2bf(float x) {
  unsigned u = __builtin_bit_cast(unsigned, x);
  return (u16)((u + 0x7fffu + ((u >> 16) & 1u)) >> 16);
}
__device__ __forceinline__ float sigf(float x) { return 1.f / (1.f + __expf(-x)); }
__device__ __forceinline__ float tanhfast(float x) {
  float e = __expf(2.f * x);
  return 1.f - 2.f / (e + 1.f);
}

// relaxed agent-scope (sc1, LLC-coherent) primitives
__device__ __forceinline__ u64 ld8_llc(const u64* p) {
  return __hip_atomic_load(p, __ATOMIC_RELAXED, __HIP_MEMORY_SCOPE_AGENT);
}
__device__ __forceinline__ void st8_llc(u64* p, u64 v) {
  __hip_atomic_store(p, v, __ATOMIC_RELAXED, __HIP_MEMORY_SCOPE_AGENT);
}
__device__ __forceinline__ short8 ld16_llc(const u16* p) {
  const u64* q = (const u64*)p;
  u64 lo = ld8_llc(q), hi = ld8_llc(q + 1);
  union { u64 v[2]; short8 s; } u;
  u.v[0] = lo; u.v[1] = hi;
  return u.s;
}
__device__ __forceinline__ void st2_llc(u16* p, u16 v) {
  __hip_atomic_store(p, v, __ATOMIC_RELAXED, __HIP_MEMORY_SCOPE_AGENT);
}
__device__ __forceinline__ void st4_llc(u32* p, u32 v) {
  __hip_atomic_store(p, v, __ATOMIC_RELAXED, __HIP_MEMORY_SCOPE_AGENT);
}
__device__ __forceinline__ u32 ld4_llc(const u32* p) {
  return __hip_atomic_load(p, __ATOMIC_RELAXED, __HIP_MEMORY_SCOPE_AGENT);
}
// poll 16 packed u32 flags (one line); lane i checks dword i&15
__device__ __forceinline__ void poll_sc1(const u32* base, int lane, u32 tgt) {
  const u32* pf = base + (lane & 15);
  for (;;) {
    u32 v = ld4_llc(pf);
    if (__all((int)(v >= tgt))) break;
    __builtin_amdgcn_s_sleep(1);
  }
  asm volatile("" ::: "memory");
}

__device__ __forceinline__ short8 cvt8(const float* src) {
  float4 lo = *(const float4*)src;
  float4 hi = *(const float4*)(src + 4);
  short8 fr;
  fr[0] = (short)f2bf(lo.x); fr[1] = (short)f2bf(lo.y);
  fr[2] = (short)f2bf(lo.z); fr[3] = (short)f2bf(lo.w);
  fr[4] = (short)f2bf(hi.x); fr[5] = (short)f2bf(hi.y);
  fr[6] = (short)f2bf(hi.z); fr[7] = (short)f2bf(hi.w);
  return fr;
}

// ---- embedding gather into MFMA-B fragment layout (bf16) ----
__global__ void gather_x0(const int* __restrict__ in_t, const float* __restrict__ emb,
                          u16* __restrict__ x0) {
  int gid = blockIdx.x * 256 + threadIdx.x;
  int c = gid >> 6, lane = gid & 63;
  int t = c >> 6, rem = c & 63;
  int kt = rem >> 2, nt = rem & 3;
  int b = nt * 16 + (lane & 15);
  int k0 = kt * 32 + ((lane >> 4) * 8);
  int row = in_t[b * T_LEN + t];
  *(short8*)(x0 + (size_t)c * CHUNK_U16 + lane * 8) =
      cvt8(emb + (size_t)row * 512 + k0);
}

// ---- persistent recurrent kernel: 32h x 16n units, tag-strip repack ----
// 128 blocks x 512 threads. bid: g=bid&7 (layer=g>>2, sq=g&3), u=bid>>3 (0..15).
// Unit: h [32u,32u+32) (128 gate-rows, m=4*h_local+gate, 8 m-tiles) x samples
// [16sq,16sq+16), full K. Waves 0-3 x-side: kt [4w,4w+4), nt=sq. Waves 4-7
// h-side: e=w-4, real kt [4e,4e+4) via tagged u64s, tag-stripped in regs.
// Domain slot: [Qp:256][n:16] u64; Qp covers h pair (2Qp,2Qp+1); u64 =
// {c_even, c_odd, tag u32}; tag==t+1 published fire-and-forget at end of step t.
// Slab rows stored PERMUTED (q in low bits: row_s = mt*16 + r*4 + q) so both
// the MFMA-partial writes and the epilogue reads are 2-way (free) on banks.
// y certification merged into b1 and amortized to every 4 steps.
__global__ __launch_bounds__(512, 1) void lstm_persist(
    const float* __restrict__ wx, const float* __restrict__ bx,
    const float* __restrict__ wh, const float* __restrict__ bh,
    const u16* __restrict__ x0, u16* __restrict__ y0,
    u16* __restrict__ hd, float* __restrict__ pool, u32* __restrict__ yflg) {
  __shared__ float part[8][128][16];   // [wave][perm-row][sample] = 64KB

  const int tid = threadIdx.x;
  const int w = tid >> 6, lane = tid & 63;
  const int q = lane >> 4, col = lane & 15;
  const int bid = blockIdx.x;
  const int g = bid & 7;
  const int layer = g >> 2, sq = g & 3;
  const int u = bid >> 3;          // 0..15
  const bool xside = (w < 4);
  const int e = w & 3;             // k-quarter for both sides

  // ---- weight fragments: 8 m-tiles x 4 real-kt = 128 regs (untagged) ----
  short8 af[8][4];
  {
    const int gt_a = col & 3, hsub = col >> 2;
    const float* wsel = xside ? wx : wh;
#pragma unroll
    for (int mt = 0; mt < 8; ++mt) {
      const int h_out = u * 32 + mt * 4 + hsub;
      const float* wrow = wsel + ((size_t)(layer * 4 + gt_a) * 512 + h_out) * 512;
#pragma unroll
      for (int ks = 0; ks < 4; ++ks)
        af[mt][ks] = cvt8(wrow + (e * 4 + ks) * 32 + q * 8);
    }
  }

  // epilogue ownership: one (h_g = 32u + hl, sample n) per thread
  const int hl = tid >> 4, n = tid & 15;   // hl 0..31, n 0..15
  const int h_g = u * 32 + hl;
  float bias[4];
#pragma unroll
  for (int r = 0; r < 4; ++r)
    bias[r] = bx[(layer * 4 + r) * 512 + h_g] + bh[(layer * 4 + r) * 512 + h_g];
  // y fragment offset: b = 16*sq + n -> nt = sq, b&15 = n
  const size_t offY = ((size_t)((h_g >> 5) * 4 + sq) * 64 +
                       n + 16 * ((h_g >> 3) & 3)) * 8 + (h_g & 7);
  // tagged u64 index (even hl stores pair (h_g, h_g+1)): Qp = 16u + hl/2
  const size_t hoff = (size_t)(16 * u + (hl >> 1)) * 16 + n;
  // permuted epilogue read rows: logical row 4*hl+gt -> storage
  // row_s = (hl>>2)*16 + gt*4 + (hl&3)
  const int rs_base = (hl >> 2) * 16 + (hl & 3);

  const u16* xbase = layer ? y0 : x0;
  u64* hdl = (u64*)hd + (size_t)g * 2 * HSLOT_U64;
  u32* yf_own = yflg + sq * 16 + u;
  const u32* yf_grp = yflg + sq * 16;

  float cst = 0.f, opool = 0.f;

  for (int t = 0; t < T_LEN; ++t) {
    f32x4 acc[8] = {};
    if (xside) {
      if (layer == 1) poll_sc1(yf_grp, lane, (u32)(t + 1));
      const u16* xs = xbase + (size_t)t * XSTEP_U16;
#pragma unroll
      for (int ks = 0; ks < 4; ++ks) {
        const int ktl = e * 4 + ks;
        const u16* p = xs + ((size_t)(ktl * 4 + sq) * 64 + lane) * 8;
        short8 f = (layer == 0) ? *(const short8*)p : ld16_llc(p);
#pragma unroll
        for (int mt = 0; mt < 8; ++mt)
          acc[mt] = __builtin_amdgcn_mfma_f32_16x16x32_bf16(af[mt][ks], f,
                                                            acc[mt], 0, 0, 0);
      }
    } else {
      // ---- h-side: tagged retry read (16 u64/thread), then strip+repack ----
      const u64* hs = hdl + (size_t)(t & 1) * HSLOT_U64;
      const u32 tagv = (u32)t;
      u64 d0[4], d1[4], d2[4], d3[4];   // [kr]: Qp+0..3 (compile-time idx)
      for (;;) {
#pragma unroll
        for (int kr = 0; kr < 4; ++kr) {
          const int ktl = e * 4 + kr;
          const u64* b0 = hs + ((size_t)(ktl * 16 + 4 * q) * 16 + col);
          d0[kr] = ld8_llc(b0);
          d1[kr] = ld8_llc(b0 + 16);
          d2[kr] = ld8_llc(b0 + 32);
          d3[kr] = ld8_llc(b0 + 48);
        }
        int ok = 1;
#pragma unroll
        for (int kr = 0; kr < 4; ++kr)
          ok &= (int)(((u32)(d0[kr] >> 32) == tagv) &
                      ((u32)(d1[kr] >> 32) == tagv) &
                      ((u32)(d2[kr] >> 32) == tagv) &
                      ((u32)(d3[kr] >> 32) == tagv));
        if (__all(ok)) break;
        __builtin_amdgcn_s_sleep(1);
      }
#pragma unroll
      for (int kr = 0; kr < 4; ++kr) {
        union { u64 v[2]; short8 s; } uf;   // strip tags: keep low-32 halves
        uf.v[0] = (u64)(u32)d0[kr] | ((u64)(u32)d1[kr] << 32);
        uf.v[1] = (u64)(u32)d2[kr] | ((u64)(u32)d3[kr] << 32);
#pragma unroll
        for (int mt = 0; mt < 8; ++mt)
          acc[mt] = __builtin_amdgcn_mfma_f32_16x16x32_bf16(af[mt][kr], uf.s,
                                                            acc[mt], 0, 0, 0);
      }
    }
    // partials -> own slab, PERMUTED row (q in low bits) -> 2-way banks (free)
#pragma unroll
    for (int mt = 0; mt < 8; ++mt)
#pragma unroll
      for (int r = 0; r < 4; ++r)
        part[w][mt * 16 + r * 4 + q][col] = acc[mt][r];

    const bool certstep = (layer == 0) && ((t & 3) == 0);
    if (certstep)
      asm volatile("s_waitcnt vmcnt(0)" ::: "memory");  // drains step-old stores
    __syncthreads();   // b1: partials ready (+ cert drains done on cert steps)
    if (certstep && tid == 1) st4_llc(yf_own, (u32)t);  // certifies y(0..t-1)

    // ---- epilogue: reduce 8 slabs (permuted rows) + gates ----
    float v[4];
#pragma unroll
    for (int gt = 0; gt < 4; ++gt) {
      const int rs = rs_base + gt * 4;
      float s = 0.f;
#pragma unroll
      for (int ww = 0; ww < 8; ++ww) s += part[ww][rs][n];
      v[gt] = s + bias[gt];
    }
    const float ig = sigf(v[0]);
    const float fg = sigf(v[1]);
    const float gg = tanhfast(v[2]);
    const float og = sigf(v[3]);
    const float cn = fg * cst + ig * gg;   // c input = prev h_new (unpack bug)
    const float hn = og * tanhfast(cn);
    cst = hn;
    const float pcn = __shfl_xor(cn, 16, 64);  // partner (hl^1) c_new
    if ((hl & 1) == 0) {   // even-hl threads store the tagged pair u64
      u64* hdst = hdl + (size_t)((t + 1) & 1) * HSLOT_U64;
      u64 val = (u64)(u16)f2bf(cn) | ((u64)(u16)f2bf(pcn) << 16) |
                ((u64)(u32)(t + 1) << 32);
      st8_llc(hdst + hoff, val);         // fire-and-forget (bug: c_new is h-input)
    }
    if (layer == 0) {
      st2_llc(y0 + (size_t)t * XSTEP_U16 + offY, f2bf(og));  // o -> L1 input
    } else {
      opool += og;
    }
    __syncthreads();   // b2: slabs fully read
  }

  if (layer == 0) {
    // final y certification (certifies y(0..255)); without it L1 deadlocks
    asm volatile("s_waitcnt vmcnt(0)" ::: "memory");
    __syncthreads();
    if (tid == 1) st4_llc(yf_own, (u32)T_LEN);
  } else {
    pool[(size_t)h_g * 64 + sq * 16 + n] = opool;
  }
}

// ---- final pooled @ wo.T + bo -> sigmoid ----
__global__ void finalize_k(const float* __restrict__ pool, const float* __restrict__ wo,
                           const float* __restrict__ bo, float* __restrict__ out) {
  const int b = threadIdx.x;
  float s = 0.f;
  for (int h = 0; h < 512; ++h) s += pool[h * 64 + b] * wo[h];
  out[b] = sigf(s * (1.f / 256.f) + bo[0]);
}

extern "C" void kernel_launch(void* const* d_in, const int* in_sizes, int n_in,
                              void* d_out, int out_size, void* d_ws, size_t ws_size,
                              hipStream_t stream) {
  const int* in_t = (const int*)d_in[0];
  const float* emb = (const float*)d_in[1];
  const float* wx = (const float*)d_in[2];
  const float* bx = (const float*)d_in[3];
  const float* wh = (const float*)d_in[4];
  const float* bh = (const float*)d_in[5];
  const float* wo = (const float*)d_in[6];
  const float* bo = (const float*)d_in[7];
  float* out = (float*)d_out;
  char* ws = (char*)d_ws;
  u16* x0 = (u16*)(ws + OFF_X0);
  u16* y0 = (u16*)(ws + OFF_Y0);
  u16* hd = (u16*)(ws + OFF_HD);
  float* pool = (float*)(ws + OFF_POOL);
  u32* yflg = (u32*)(ws + OFF_YFLG);

  hipMemsetAsync(ws + OFF_HD, 0, SZ_HD, stream);     // h(0)=0, tags=0
  hipMemsetAsync(ws + OFF_YFLG, 0, SZ_YFLG, stream); // y flags
  gather_x0<<<4096, 256, 0, stream>>>(in_t, emb, x0);
  lstm_persist<<<128, 512, 0, stream>>>(wx, bx, wh, bh, x0, y0, hd, pool, yflg);
  finalize_k<<<1, 64, 0, stream>>>(pool, wo, bo, out);
}

// Round 20
// 700.567 us; speedup vs baseline: 8.3659x; 1.0109x over previous
//
#include <hip/hip_runtime.h>

typedef __attribute__((ext_vector_type(8))) short short8;
typedef __attribute__((ext_vector_type(4))) float f32x4;
typedef unsigned short u16;
typedef unsigned int u32;
typedef unsigned long long u64;

#define T_LEN 256
#define XSTEP_U16 32768      // x/y per-t: [kt:16][nt:4][512] u16 = 64KB
#define CHUNK_U16 512
#define HSLOT_U64 4096       // per (layer,sq) slot: 256 Qp x 16 n u64 = 32KB

// workspace layout (bytes)
#define OFF_X0 0u
#define SZ_X0 (256u * 65536u)   // 16MB
#define OFF_Y0 (OFF_X0 + SZ_X0)
#define SZ_Y0 SZ_X0             // 16MB
#define OFF_HD (OFF_Y0 + SZ_Y0)
#define SZ_HD (8u * 2u * 32768u)  // 8 (layer,sq) domains x 2 slots x 32KB
#define OFF_POOL (OFF_HD + SZ_HD)
#define SZ_POOL (512u * 64u * 4u)
#define OFF_YFLG (OFF_POOL + SZ_POOL)
#define SZ_YFLG (4u * 16u * 4u)   // [sq][16 units] packed u32

__device__ __forceinline__ u16 f2bf(float x) {
  unsigned u = __builtin_bit_cast(unsigned, x);
  return (u16)((u + 0x7fffu + ((u >> 16) & 1u)) >> 16);
}
__device__ __forceinline__ float sigf(float x) { return 1.f / (1.f + __expf(-x)); }
__device__ __forceinline__ float tanhfast(float x) {
  float e = __expf(2.f * x);
  return 1.f - 2.f / (e + 1.f);
}

// relaxed agent-scope (sc1, LLC-coherent) primitives
__device__ __forceinline__ u64 ld8_llc(const u64* p) {
  return __hip_atomic_load(p, __ATOMIC_RELAXED, __HIP_MEMORY_SCOPE_AGENT);
}
__device__ __forceinline__ void st8_llc(u64* p, u64 v) {
  __hip_atomic_store(p, v, __ATOMIC_RELAXED, __HIP_MEMORY_SCOPE_AGENT);
}
__device__ __forceinline__ short8 ld16_llc(const u16* p) {
  const u64* q = (const u64*)p;
  u64 lo = ld8_llc(q), hi = ld8_llc(q + 1);
  union { u64 v[2]; short8 s; } u;
  u.v[0] = lo; u.v[1] = hi;
  return u.s;
}
__device__ __forceinline__ void st2_llc(u16* p, u16 v) {
  __hip_atomic_store(p, v, __ATOMIC_RELAXED, __HIP_MEMORY_SCOPE_AGENT);
}
__device__ __forceinline__ void st4_llc(u32* p, u32 v) {
  __hip_atomic_store(p, v, __ATOMIC_RELAXED, __HIP_MEMORY_SCOPE_AGENT);
}
__device__ __forceinline__ u32 ld4_llc(const u32* p) {
  return __hip_atomic_load(p, __ATOMIC_RELAXED, __HIP_MEMORY_SCOPE_AGENT);
}
// poll 16 packed u32 flags (one line); lane i checks dword i&15
__device__ __forceinline__ void poll_sc1(const u32* base, int lane, u32 tgt) {
  const u32* pf = base + (lane & 15);
  for (;;) {
    u32 v = ld4_llc(pf);
    if (__all((int)(v >= tgt))) break;
    __builtin_amdgcn_s_sleep(1);
  }
  asm volatile("" ::: "memory");
}

__device__ __forceinline__ short8 cvt8(const float* src) {
  float4 lo = *(const float4*)src;
  float4 hi = *(const float4*)(src + 4);
  short8 fr;
  fr[0] = (short)f2bf(lo.x); fr[1] = (short)f2bf(lo.y);
  fr[2] = (short)f2bf(lo.z); fr[3] = (short)f2bf(lo.w);
  fr[4] = (short)f2bf(hi.x); fr[5] = (short)f2bf(hi.y);
  fr[6] = (short)f2bf(hi.z); fr[7] = (short)f2bf(hi.w);
  return fr;
}

// ---- embedding gather into MFMA-B fragment layout (bf16) ----
__global__ void gather_x0(const int* __restrict__ in_t, const float* __restrict__ emb,
                          u16* __restrict__ x0) {
  int gid = blockIdx.x * 256 + threadIdx.x;
  int c = gid >> 6, lane = gid & 63;
  int t = c >> 6, rem = c & 63;
  int kt = rem >> 2, nt = rem & 3;
  int b = nt * 16 + (lane & 15);
  int k0 = kt * 32 + ((lane >> 4) * 8);
  int row = in_t[b * T_LEN + t];
  *(short8*)(x0 + (size_t)c * CHUNK_U16 + lane * 8) =
      cvt8(emb + (size_t)row * 512 + k0);
}

// ---- persistent recurrent kernel: 32h x 16n units, tag-strip repack ----
// 128 blocks x 512 threads. bid: g=bid&7 (layer=g>>2, sq=g&3), u=bid>>3 (0..15).
// Unit: h [32u,32u+32) (128 gate-rows, m=4*h_local+gate, 8 m-tiles) x samples
// [16sq,16sq+16), full K. Waves 0-3 x-side: kt [4w,4w+4), nt=sq. Waves 4-7
// h-side: e=w-4, real kt [4e,4e+4) via tagged u64s, tag-stripped in regs.
// Domain slot: [Qp:256][n:16] u64; Qp covers h pair (2Qp,2Qp+1); u64 =
// {c_even, c_odd, tag u32}; tag==t+1 published fire-and-forget at end of step t.
// Slab rows stored PERMUTED (row_s = mt*16 + r*4 + q) -> conflict-free LDS.
// b2 placed right after slab reads: gates/stores run OUTSIDE barriers and
// overlap the next step's poll/load phase.
__global__ __launch_bounds__(512, 1) void lstm_persist(
    const float* __restrict__ wx, const float* __restrict__ bx,
    const float* __restrict__ wh, const float* __restrict__ bh,
    const u16* __restrict__ x0, u16* __restrict__ y0,
    u16* __restrict__ hd, float* __restrict__ pool, u32* __restrict__ yflg) {
  __shared__ float part[8][128][16];   // [wave][perm-row][sample] = 64KB

  const int tid = threadIdx.x;
  const int w = tid >> 6, lane = tid & 63;
  const int q = lane >> 4, col = lane & 15;
  const int bid = blockIdx.x;
  const int g = bid & 7;
  const int layer = g >> 2, sq = g & 3;
  const int u = bid >> 3;          // 0..15
  const bool xside = (w < 4);
  const int e = w & 3;             // k-quarter for both sides

  // ---- weight fragments: 8 m-tiles x 4 real-kt = 128 regs (untagged) ----
  short8 af[8][4];
  {
    const int gt_a = col & 3, hsub = col >> 2;
    const float* wsel = xside ? wx : wh;
#pragma unroll
    for (int mt = 0; mt < 8; ++mt) {
      const int h_out = u * 32 + mt * 4 + hsub;
      const float* wrow = wsel + ((size_t)(layer * 4 + gt_a) * 512 + h_out) * 512;
#pragma unroll
      for (int ks = 0; ks < 4; ++ks)
        af[mt][ks] = cvt8(wrow + (e * 4 + ks) * 32 + q * 8);
    }
  }

  // epilogue ownership: one (h_g = 32u + hl, sample n) per thread
  const int hl = tid >> 4, n = tid & 15;   // hl 0..31, n 0..15
  const int h_g = u * 32 + hl;
  float bias[4];
#pragma unroll
  for (int r = 0; r < 4; ++r)
    bias[r] = bx[(layer * 4 + r) * 512 + h_g] + bh[(layer * 4 + r) * 512 + h_g];
  // y fragment offset: b = 16*sq + n -> nt = sq, b&15 = n
  const size_t offY = ((size_t)((h_g >> 5) * 4 + sq) * 64 +
                       n + 16 * ((h_g >> 3) & 3)) * 8 + (h_g & 7);
  // tagged u64 index (even hl stores pair (h_g, h_g+1)): Qp = 16u + hl/2
  const size_t hoff = (size_t)(16 * u + (hl >> 1)) * 16 + n;
  // permuted epilogue read rows: logical row 4*hl+gt -> storage
  // row_s = (hl>>2)*16 + gt*4 + (hl&3)
  const int rs_base = (hl >> 2) * 16 + (hl & 3);

  const u16* xbase = layer ? y0 : x0;
  u64* hdl = (u64*)hd + (size_t)g * 2 * HSLOT_U64;
  u32* yf_own = yflg + sq * 16 + u;
  const u32* yf_grp = yflg + sq * 16;

  float cst = 0.f, opool = 0.f;

  for (int t = 0; t < T_LEN; ++t) {
    f32x4 acc[8] = {};
    if (xside) {
      if (layer == 1) poll_sc1(yf_grp, lane, (u32)(t + 1));
      const u16* xs = xbase + (size_t)t * XSTEP_U16;
#pragma unroll
      for (int ks = 0; ks < 4; ++ks) {
        const int ktl = e * 4 + ks;
        const u16* p = xs + ((size_t)(ktl * 4 + sq) * 64 + lane) * 8;
        short8 f = (layer == 0) ? *(const short8*)p : ld16_llc(p);
#pragma unroll
        for (int mt = 0; mt < 8; ++mt)
          acc[mt] = __builtin_amdgcn_mfma_f32_16x16x32_bf16(af[mt][ks], f,
                                                            acc[mt], 0, 0, 0);
      }
    } else {
      // ---- h-side: tagged retry read (16 u64/thread), then strip+repack ----
      const u64* hs = hdl + (size_t)(t & 1) * HSLOT_U64;
      const u32 tagv = (u32)t;
      u64 d0[4], d1[4], d2[4], d3[4];   // [kr]: Qp+0..3 (compile-time idx)
      for (;;) {
#pragma unroll
        for (int kr = 0; kr < 4; ++kr) {
          const int ktl = e * 4 + kr;
          const u64* b0 = hs + ((size_t)(ktl * 16 + 4 * q) * 16 + col);
          d0[kr] = ld8_llc(b0);
          d1[kr] = ld8_llc(b0 + 16);
          d2[kr] = ld8_llc(b0 + 32);
          d3[kr] = ld8_llc(b0 + 48);
        }
        int ok = 1;
#pragma unroll
        for (int kr = 0; kr < 4; ++kr)
          ok &= (int)(((u32)(d0[kr] >> 32) == tagv) &
                      ((u32)(d1[kr] >> 32) == tagv) &
                      ((u32)(d2[kr] >> 32) == tagv) &
                      ((u32)(d3[kr] >> 32) == tagv));
        if (__all(ok)) break;
        __builtin_amdgcn_s_sleep(1);
      }
#pragma unroll
      for (int kr = 0; kr < 4; ++kr) {
        union { u64 v[2]; short8 s; } uf;   // strip tags: keep low-32 halves
        uf.v[0] = (u64)(u32)d0[kr] | ((u64)(u32)d1[kr] << 32);
        uf.v[1] = (u64)(u32)d2[kr] | ((u64)(u32)d3[kr] << 32);
#pragma unroll
        for (int mt = 0; mt < 8; ++mt)
          acc[mt] = __builtin_amdgcn_mfma_f32_16x16x32_bf16(af[mt][kr], uf.s,
                                                            acc[mt], 0, 0, 0);
      }
    }
    // partials -> own slab, PERMUTED row (q in low bits) -> conflict-free
#pragma unroll
    for (int mt = 0; mt < 8; ++mt)
#pragma unroll
      for (int r = 0; r < 4; ++r)
        part[w][mt * 16 + r * 4 + q][col] = acc[mt][r];

    const bool certstep = (layer == 0) && ((t & 3) == 0);
    if (certstep)
      asm volatile("s_waitcnt vmcnt(0)" ::: "memory");  // drains step-old stores
    __syncthreads();   // b1: partials ready (+ cert drains done on cert steps)
    if (certstep && tid == 1) st4_llc(yf_own, (u32)t);  // certifies y(0..t-1)

    // ---- epilogue: capture slab values into regs, then release LDS ----
    float v[4];
#pragma unroll
    for (int gt = 0; gt < 4; ++gt) {
      const int rs = rs_base + gt * 4;
      float s = 0.f;
#pragma unroll
      for (int ww = 0; ww < 8; ++ww) s += part[ww][rs][n];
      v[gt] = s + bias[gt];
    }
    __syncthreads();   // b2 (early): all reads done; next-step writes safe

    // ---- gates + stores OUTSIDE barrier region (overlap next poll/load) ----
    const float ig = sigf(v[0]);
    const float fg = sigf(v[1]);
    const float gg = tanhfast(v[2]);
    const float og = sigf(v[3]);
    const float cn = fg * cst + ig * gg;   // c input = prev h_new (unpack bug)
    const float hn = og * tanhfast(cn);
    cst = hn;
    const float pcn = __shfl_xor(cn, 16, 64);  // partner (hl^1) c_new
    if ((hl & 1) == 0) {   // even-hl threads store the tagged pair u64
      u64* hdst = hdl + (size_t)((t + 1) & 1) * HSLOT_U64;
      u64 val = (u64)(u16)f2bf(cn) | ((u64)(u16)f2bf(pcn) << 16) |
                ((u64)(u32)(t + 1) << 32);
      st8_llc(hdst + hoff, val);         // fire-and-forget (bug: c_new is h-input)
    }
    if (layer == 0) {
      st2_llc(y0 + (size_t)t * XSTEP_U16 + offY, f2bf(og));  // o -> L1 input
    } else {
      opool += og;
    }
  }

  if (layer == 0) {
    // final y certification (certifies y(0..255)); without it L1 deadlocks
    asm volatile("s_waitcnt vmcnt(0)" ::: "memory");
    __syncthreads();
    if (tid == 1) st4_llc(yf_own, (u32)T_LEN);
  } else {
    pool[(size_t)h_g * 64 + sq * 16 + n] = opool;
  }
}

// ---- final pooled @ wo.T + bo -> sigmoid ----
__global__ void finalize_k(const float* __restrict__ pool, const float* __restrict__ wo,
                           const float* __restrict__ bo, float* __restrict__ out) {
  const int b = threadIdx.x;
  float s = 0.f;
  for (int h = 0; h < 512; ++h) s += pool[h * 64 + b] * wo[h];
  out[b] = sigf(s * (1.f / 256.f) + bo[0]);
}

extern "C" void kernel_launch(void* const* d_in, const int* in_sizes, int n_in,
                              void* d_out, int out_size, void* d_ws, size_t ws_size,
                              hipStream_t stream) {
  const int* in_t = (const int*)d_in[0];
  const float* emb = (const float*)d_in[1];
  const float* wx = (const float*)d_in[2];
  const float* bx = (const float*)d_in[3];
  const float* wh = (const float*)d_in[4];
  const float* bh = (const float*)d_in[5];
  const float* wo = (const float*)d_in[6];
  const float* bo = (const float*)d_in[7];
  float* out = (float*)d_out;
  char* ws = (char*)d_ws;
  u16* x0 = (u16*)(ws + OFF_X0);
  u16* y0 = (u16*)(ws + OFF_Y0);
  u16* hd = (u16*)(ws + OFF_HD);
  float* pool = (float*)(ws + OFF_POOL);
  u32* yflg = (u32*)(ws + OFF_YFLG);

  hipMemsetAsync(ws + OFF_HD, 0, SZ_HD, stream);     // h(0)=0, tags=0
  hipMemsetAsync(ws + OFF_YFLG, 0, SZ_YFLG, stream); // y flags
  gather_x0<<<4096, 256, 0, stream>>>(in_t, emb, x0);
  lstm_persist<<<128, 512, 0, stream>>>(wx, bx, wh, bh, x0, y0, hd, pool, yflg);
  finalize_k<<<1, 64, 0, stream>>>(pool, wo, bo, out);
}